// Round 5
// baseline (6448.919 us; speedup 1.0000x reference)
//
#include <hip/hip_runtime.h>

typedef __attribute__((ext_vector_type(2))) float f32x2;
typedef __attribute__((ext_vector_type(4))) float f32x4;
typedef __attribute__((ext_vector_type(8))) short short8;
typedef __attribute__((ext_vector_type(4))) short short4v;

// Padded LDS layout: logical index I -> word I + (I>>4); one pad word per 16.
// Lane addresses become 17*t + const  => exactly 2 lanes/bank => conflict-free.
#define PADW(I) ((I) + ((I) >> 4))
// Affine form: PADW(16*t + z) == 17*t + WOFF(z), WOFF compile-time constant.
#define WOFF(z) ((z) + ((z) >> 4))

constexpr int LROW = 4096;
constexpr int KW   = 64;
constexpr int HALO = 32;                      // pad_lo=31, pad_hi=32
constexpr int NLOG = LROW + 2 * HALO;         // 4160
constexpr int XS_SIZE = PADW(NLOG - 1) + 1;   // 4419 words

__device__ __forceinline__ float shrinkf(float c, float theta) {
  float a = fabsf(c) - theta;
  return (a > 0.0f) ? copysignf(a, c) : 0.0f;
}

// One block = one row. Thread t owns outputs i in [16t, 16t+16).
// acc[e] = sum_j kn[j] * x[16t+e-31+j]; window w[m] = x[16t-31+m], m=e+j.
// Pair form over even j: acc2[e] += (kn[j],kn[j+1]) * (w[e+j], w[e+j+1]);
// final acc[e] = acc2[e].x + acc2[e].y  -> v_pk_fma_f32 candidates.
__global__ __launch_bounds__(256, 3) void ista_pk(
    const float* __restrict__ y, const float* __restrict__ pulse,
    float* __restrict__ xout) {
  __shared__ float xs[XS_SIZE];
  __shared__ float pl[KW];
  __shared__ float knl[KW];

  const int t = threadIdx.x;
  const int row = blockIdx.x;

  if (t < KW) pl[t] = pulse[t];
  if (t < HALO) {                       // zero halos (stay zero forever)
    xs[PADW(t)] = 0.0f;
    xs[PADW(NLOG - HALO + t)] = 0.0f;
  }
  // stage y row into xs (coalesced float4 loads)
  const float* yrow = y + (size_t)row * LROW;
#pragma unroll
  for (int q = 0; q < 4; ++q) {
    int i4 = q * 256 + t;
    float4 v = ((const float4*)yrow)[i4];
    xs[PADW(HALO + 4 * i4 + 0)] = v.x;
    xs[PADW(HALO + 4 * i4 + 1)] = v.y;
    xs[PADW(HALO + 4 * i4 + 2)] = v.z;
    xs[PADW(HALO + 4 * i4 + 3)] = v.w;
  }
  __syncthreads();

  float Lc = 0.0f;
#pragma unroll
  for (int j = 0; j < KW; ++j) Lc += pl[j] * pl[j];
  const float theta = 0.1f / Lc;
  if (t < KW) knl[t] = pl[KW - 1 - t] / Lc;   // reversed pulse, pre-divided by L
  __syncthreads();

  // kernel pairs in registers (iteration-invariant): kn2[h] = (kn[2h], kn[2h+1])
  f32x2 kn2[32];
#pragma unroll
  for (int h = 0; h < 32; ++h) {
    kn2[h][0] = knl[2 * h];
    kn2[h][1] = knl[2 * h + 1];
  }

  float* xw = xs + 17 * t;   // affine base; all accesses use immediate offsets

  auto conv_pk = [&](float out[16]) {
    f32x2 a2[16];
#pragma unroll
    for (int e = 0; e < 16; ++e) a2[e] = (f32x2)0.0f;
#pragma unroll
    for (int p = 0; p < 78; ++p) {       // pair_p = (w[p], w[p+1])
      f32x2 w2;
      w2[0] = xw[WOFF(1 + p)];
      w2[1] = xw[WOFF(2 + p)];
#pragma unroll
      for (int e = (p & 1); e < 16; e += 2) {
        const int j = p - e;             // even by construction
        if (0 <= j && j <= 62)
          a2[e] = __builtin_elementwise_fma(kn2[j >> 1], w2, a2[e]);
      }
    }
#pragma unroll
    for (int e = 0; e < 16; ++e) out[e] = a2[e][0] + a2[e][1];
  };

  // B_term = conv(y)/L, kept in registers
  float bt[16];
  conv_pk(bt);
  __syncthreads();                       // all reads of y done before overwrite

  // iteration 1: x1 = shrink(B_term)
#pragma unroll
  for (int e = 0; e < 16; ++e) xw[WOFF(32 + e)] = shrinkf(bt[e], theta);
  __syncthreads();

  // 19 remaining iterations, in-place single buffer (read-all, sync, write, sync)
  for (int it = 0; it < 19; ++it) {
    float acc[16];
    conv_pk(acc);
    float xn[16];
#pragma unroll
    for (int e = 0; e < 16; ++e) {
      float xc = xw[WOFF(32 + e)];
      xn[e] = shrinkf(bt[e] + xc - acc[e], theta);
    }
    __syncthreads();                     // all reads of old x complete
#pragma unroll
    for (int e = 0; e < 16; ++e) xw[WOFF(32 + e)] = xn[e];
    __syncthreads();                     // new x visible to all
  }

  // write x out, coalesced float4
  float* xr = xout + (size_t)row * LROW;
#pragma unroll
  for (int q = 0; q < 4; ++q) {
    int i4 = q * 256 + t;
    float4 v;
    v.x = xs[PADW(HALO + 4 * i4 + 0)];
    v.y = xs[PADW(HALO + 4 * i4 + 1)];
    v.z = xs[PADW(HALO + 4 * i4 + 2)];
    v.w = xs[PADW(HALO + 4 * i4 + 3)];
    ((float4*)xr)[i4] = v;
  }
}

// ---------------- MLP via bf16 MFMA (validated in R2) ----------------
__device__ __forceinline__ unsigned short f2bf(float f) {
  unsigned u = __float_as_uint(f);
  u += 0x7fffu + ((u >> 16) & 1u);      // RNE
  return (unsigned short)(u >> 16);
}

__global__ __launch_bounds__(256) void cast_w1(const float* __restrict__ W1,
                                               unsigned short* __restrict__ W1p) {
  const int kq = blockIdx.x;
  const int c  = threadIdx.x;
  short8 v;
#pragma unroll
  for (int j = 0; j < 8; ++j)
    v[j] = (short)f2bf(W1[(size_t)(kq * 8 + j) * 256 + c]);
  *(short8*)(W1p + ((size_t)kq * 256 + c) * 8) = v;
}

__global__ __launch_bounds__(256) void mlp_mfma(
    const float* __restrict__ x, const unsigned short* __restrict__ W1p,
    const float* __restrict__ b1, const float* __restrict__ W2,
    const float* __restrict__ b2, float* __restrict__ out1) {
  __shared__ short Ap[16 * 8 * 8];
  __shared__ short Bp[8 * 256 * 8];
  __shared__ float pr[4][16];

  const int t = threadIdx.x;
  const int w = t >> 6;
  const int l = t & 63;
  const int lrow = l & 15;
  const int lk   = l >> 4;
  const int row0 = blockIdx.x * 16;

  f32x4 acc[4];
#pragma unroll
  for (int n = 0; n < 4; ++n) acc[n] = (f32x4)0.0f;

  for (int kt = 0; kt < 64; ++kt) {
    __syncthreads();
    {
      const int r  = t >> 4;
      const int k4 = t & 15;
      const float4 v = *(const float4*)(x + (size_t)(row0 + r) * LROW + kt * 64 + k4 * 4);
      short4v a;
      a.x = (short)f2bf(v.x); a.y = (short)f2bf(v.y);
      a.z = (short)f2bf(v.z); a.w = (short)f2bf(v.w);
      const int kq = k4 >> 1, h = k4 & 1;
      *(short4v*)((char*)Ap + ((r * 8 + (kq ^ (r & 7))) * 16 + h * 8)) = a;
    }
    {
      const short8* src = (const short8*)(W1p + (size_t)kt * (8 * 256 * 8));
      short8* dst = (short8*)Bp;
#pragma unroll
      for (int i = 0; i < 8; ++i) dst[t + 256 * i] = src[t + 256 * i];
    }
    __syncthreads();
#pragma unroll
    for (int kf = 0; kf < 2; ++kf) {
      const int kq = kf * 4 + lk;
      short8 af = *(short8*)((char*)Ap + (lrow * 8 + (kq ^ (lrow & 7))) * 16);
#pragma unroll
      for (int n = 0; n < 4; ++n) {
        short8 bf = *(short8*)((char*)Bp + (kq * 256 + w * 64 + n * 16 + lrow) * 16);
        acc[n] = __builtin_amdgcn_mfma_f32_16x16x32_bf16(af, bf, acc[n], 0, 0, 0);
      }
    }
  }

  float s[4] = {0.0f, 0.0f, 0.0f, 0.0f};
#pragma unroll
  for (int n = 0; n < 4; ++n) {
    const int c = w * 64 + n * 16 + lrow;
    const float b1v = b1[c];
    const float w2v = W2[c];
#pragma unroll
    for (int i = 0; i < 4; ++i) {
      float f = acc[n][i] + b1v;
      f = fmaxf(f, 0.0f);
      s[i] = fmaf(f, w2v, s[i]);
    }
  }
#pragma unroll
  for (int off = 1; off < 16; off <<= 1) {
#pragma unroll
    for (int i = 0; i < 4; ++i) s[i] += __shfl_xor(s[i], off, 64);
  }
  if (lrow == 0) {
#pragma unroll
    for (int i = 0; i < 4; ++i) pr[w][lk * 4 + i] = s[i];
  }
  __syncthreads();
  if (t < 16) {
    out1[row0 + t] =
        (pr[0][t] + pr[1][t] + pr[2][t] + pr[3][t] + b2[0]) * (float)LROW;
  }
}

extern "C" void kernel_launch(void* const* d_in, const int* in_sizes, int n_in,
                              void* d_out, int out_size, void* d_ws, size_t ws_size,
                              hipStream_t stream) {
  const float* y     = (const float*)d_in[0];
  const float* pulse = (const float*)d_in[1];
  const float* W1    = (const float*)d_in[2];
  const float* b1    = (const float*)d_in[3];
  const float* W2    = (const float*)d_in[4];
  const float* b2    = (const float*)d_in[5];

  float* xout = (float*)d_out;
  float* out1 = xout + (size_t)LROW * LROW;
  unsigned short* W1p = (unsigned short*)d_ws;

  cast_w1<<<512, 256, 0, stream>>>(W1, W1p);
  ista_pk<<<LROW, 256, 0, stream>>>(y, pulse, xout);
  mlp_mfma<<<LROW / 16, 256, 0, stream>>>(xout, W1p, b1, W2, b2, out1);
}

// Round 6
// 526.901 us; speedup vs baseline: 12.2393x; 12.2393x over previous
//
#include <hip/hip_runtime.h>

typedef __attribute__((ext_vector_type(4))) float f32x4;
typedef __attribute__((ext_vector_type(8))) short short8;
typedef __attribute__((ext_vector_type(4))) short short4v;

// Padded LDS layout: logical index I -> word I + (I>>4); one pad word per 16.
// Lane addresses are 17*t + const => exactly 2 lanes/bank => conflict-free.
#define PADW(I) ((I) + ((I) >> 4))
// Affine form: PADW(16*t + z) == 17*t + WOFF(z), WOFF(z) compile-time.
#define WOFF(z) ((z) + ((z) >> 4))

constexpr int LROW = 4096;
constexpr int KW   = 64;
constexpr int HALO = 32;                      // pad_lo=31, pad_hi=32
constexpr int NLOG = LROW + 2 * HALO;         // 4160
constexpr int XS_SIZE = PADW(NLOG - 1) + 1;   // 4419 words

__device__ __forceinline__ float shrinkf(float c, float theta) {
  float a = fabsf(c) - theta;
  return (a > 0.0f) ? copysignf(a, c) : 0.0f;
}

// conv over this thread's 16 consecutive outputs with rolling-window reuse.
// xw = xs + 17*t (affine base); all LDS accesses use immediate offsets.
// acc[e] = sum_j kn[j] * x[16t+e-31+j]; window value m covers pairs e+j==m.
__device__ __forceinline__ void conv_row(const float* __restrict__ xw,
                                         const float* __restrict__ kn,
                                         float acc[16]) {
#pragma unroll
  for (int e = 0; e < 16; ++e) acc[e] = 0.0f;
#pragma unroll
  for (int m = 0; m < 79; ++m) {
    float wv = xw[WOFF(1 + m)];
    const int jlo = (m - 15 > 0) ? (m - 15) : 0;
    const int jhi = (m < 63) ? m : 63;
#pragma unroll
    for (int j = jlo; j <= jhi; ++j) {
      acc[m - j] = fmaf(kn[j], wv, acc[m - j]);
    }
  }
}

__global__ __launch_bounds__(256) void ista_kernel(
    const float* __restrict__ y, const float* __restrict__ pulse,
    float* __restrict__ xout) {
  __shared__ float xs[XS_SIZE];
  __shared__ float pl[KW];
  __shared__ float kn[KW];

  const int t = threadIdx.x;
  const int row = blockIdx.x;

  if (t < KW) pl[t] = pulse[t];
  if (t < HALO) {                       // zero halos (stay zero forever)
    xs[PADW(t)] = 0.0f;
    xs[PADW(NLOG - HALO + t)] = 0.0f;
  }
  // stage y row into xs (coalesced float4 loads)
  const float* yrow = y + (size_t)row * LROW;
#pragma unroll
  for (int q = 0; q < 4; ++q) {
    int i4 = q * 256 + t;
    float4 v = ((const float4*)yrow)[i4];
    xs[PADW(HALO + 4 * i4 + 0)] = v.x;
    xs[PADW(HALO + 4 * i4 + 1)] = v.y;
    xs[PADW(HALO + 4 * i4 + 2)] = v.z;
    xs[PADW(HALO + 4 * i4 + 3)] = v.w;
  }
  __syncthreads();

  // L_const = sum pulse^2 (redundant per-thread, broadcast LDS reads, once)
  float Lc = 0.0f;
#pragma unroll
  for (int j = 0; j < KW; ++j) Lc += pl[j] * pl[j];
  const float theta = 0.1f / Lc;
  if (t < KW) kn[t] = pl[KW - 1 - t] / Lc;   // reversed pulse, pre-divided by L
  __syncthreads();

  float* xw = xs + 17 * t;              // affine base for this thread

  // B_term = conv(y)/L (kn already folded); kept in registers for all iters
  float bt[16];
  conv_row(xw, kn, bt);
  __syncthreads();

  // iteration 1: x1 = shrink(B_term)  (x0 = 0 => conv term vanishes)
#pragma unroll
  for (int e = 0; e < 16; ++e)
    xw[WOFF(32 + e)] = shrinkf(bt[e], theta);
  __syncthreads();

  // remaining 19 ISTA iterations entirely in LDS/registers
  for (int it = 0; it < 19; ++it) {
    float acc[16];
    conv_row(xw, kn, acc);
    float xn[16];
#pragma unroll
    for (int e = 0; e < 16; ++e) {
      float xcur = xw[WOFF(32 + e)];
      xn[e] = shrinkf(bt[e] + xcur - acc[e], theta);
    }
    __syncthreads();                     // all reads of old x done
#pragma unroll
    for (int e = 0; e < 16; ++e) xw[WOFF(32 + e)] = xn[e];
    __syncthreads();                     // new x visible to all
  }

  // write x out, coalesced float4
  float* xr = xout + (size_t)row * LROW;
#pragma unroll
  for (int q = 0; q < 4; ++q) {
    int i4 = q * 256 + t;
    float4 v;
    v.x = xs[PADW(HALO + 4 * i4 + 0)];
    v.y = xs[PADW(HALO + 4 * i4 + 1)];
    v.z = xs[PADW(HALO + 4 * i4 + 2)];
    v.w = xs[PADW(HALO + 4 * i4 + 3)];
    ((float4*)xr)[i4] = v;
  }
}

// ---------------- MLP via bf16 MFMA (validated in R2) ----------------
__device__ __forceinline__ unsigned short f2bf(float f) {
  unsigned u = __float_as_uint(f);
  u += 0x7fffu + ((u >> 16) & 1u);      // RNE
  return (unsigned short)(u >> 16);
}

__global__ __launch_bounds__(256) void cast_w1(const float* __restrict__ W1,
                                               unsigned short* __restrict__ W1p) {
  const int kq = blockIdx.x;
  const int c  = threadIdx.x;
  short8 v;
#pragma unroll
  for (int j = 0; j < 8; ++j)
    v[j] = (short)f2bf(W1[(size_t)(kq * 8 + j) * 256 + c]);
  *(short8*)(W1p + ((size_t)kq * 256 + c) * 8) = v;
}

__global__ __launch_bounds__(256) void mlp_mfma(
    const float* __restrict__ x, const unsigned short* __restrict__ W1p,
    const float* __restrict__ b1, const float* __restrict__ W2,
    const float* __restrict__ b2, float* __restrict__ out1) {
  __shared__ short Ap[16 * 8 * 8];
  __shared__ short Bp[8 * 256 * 8];
  __shared__ float pr[4][16];

  const int t = threadIdx.x;
  const int w = t >> 6;
  const int l = t & 63;
  const int lrow = l & 15;
  const int lk   = l >> 4;
  const int row0 = blockIdx.x * 16;

  f32x4 acc[4];
#pragma unroll
  for (int n = 0; n < 4; ++n) acc[n] = (f32x4)0.0f;

  for (int kt = 0; kt < 64; ++kt) {
    __syncthreads();
    {
      const int r  = t >> 4;
      const int k4 = t & 15;
      const float4 v = *(const float4*)(x + (size_t)(row0 + r) * LROW + kt * 64 + k4 * 4);
      short4v a;
      a.x = (short)f2bf(v.x); a.y = (short)f2bf(v.y);
      a.z = (short)f2bf(v.z); a.w = (short)f2bf(v.w);
      const int kq = k4 >> 1, h = k4 & 1;
      *(short4v*)((char*)Ap + ((r * 8 + (kq ^ (r & 7))) * 16 + h * 8)) = a;
    }
    {
      const short8* src = (const short8*)(W1p + (size_t)kt * (8 * 256 * 8));
      short8* dst = (short8*)Bp;
#pragma unroll
      for (int i = 0; i < 8; ++i) dst[t + 256 * i] = src[t + 256 * i];
    }
    __syncthreads();
#pragma unroll
    for (int kf = 0; kf < 2; ++kf) {
      const int kq = kf * 4 + lk;
      short8 af = *(short8*)((char*)Ap + (lrow * 8 + (kq ^ (lrow & 7))) * 16);
#pragma unroll
      for (int n = 0; n < 4; ++n) {
        short8 bf = *(short8*)((char*)Bp + (kq * 256 + w * 64 + n * 16 + lrow) * 16);
        acc[n] = __builtin_amdgcn_mfma_f32_16x16x32_bf16(af, bf, acc[n], 0, 0, 0);
      }
    }
  }

  float s[4] = {0.0f, 0.0f, 0.0f, 0.0f};
#pragma unroll
  for (int n = 0; n < 4; ++n) {
    const int c = w * 64 + n * 16 + lrow;
    const float b1v = b1[c];
    const float w2v = W2[c];
#pragma unroll
    for (int i = 0; i < 4; ++i) {
      float f = acc[n][i] + b1v;
      f = fmaxf(f, 0.0f);
      s[i] = fmaf(f, w2v, s[i]);
    }
  }
#pragma unroll
  for (int off = 1; off < 16; off <<= 1) {
#pragma unroll
    for (int i = 0; i < 4; ++i) s[i] += __shfl_xor(s[i], off, 64);
  }
  if (lrow == 0) {
#pragma unroll
    for (int i = 0; i < 4; ++i) pr[w][lk * 4 + i] = s[i];
  }
  __syncthreads();
  if (t < 16) {
    out1[row0 + t] =
        (pr[0][t] + pr[1][t] + pr[2][t] + pr[3][t] + b2[0]) * (float)LROW;
  }
}

extern "C" void kernel_launch(void* const* d_in, const int* in_sizes, int n_in,
                              void* d_out, int out_size, void* d_ws, size_t ws_size,
                              hipStream_t stream) {
  const float* y     = (const float*)d_in[0];
  const float* pulse = (const float*)d_in[1];
  const float* W1    = (const float*)d_in[2];
  const float* b1    = (const float*)d_in[3];
  const float* W2    = (const float*)d_in[4];
  const float* b2    = (const float*)d_in[5];

  float* xout = (float*)d_out;
  float* out1 = xout + (size_t)LROW * LROW;
  unsigned short* W1p = (unsigned short*)d_ws;

  cast_w1<<<512, 256, 0, stream>>>(W1, W1p);
  ista_kernel<<<LROW, 256, 0, stream>>>(y, pulse, xout);
  mlp_mfma<<<LROW / 16, 256, 0, stream>>>(xout, W1p, b1, W2, b2, out1);
}